// Round 2
// baseline (344.124 us; speedup 1.0000x reference)
//
#include <hip/hip_runtime.h>

// GAT forward — MFMA GEMM + direct CSR scatter + fused softmax-aggregate:
//   0. prep: build Wswz (bf16 W^T, 16B-chunk XOR swizzle) + zero deg
//   1. front (fused): blocks [0,GB): MFMA gemm -> ftb + fused head-0 scores;
//      blocks [GB,GB+HB): per-dst degree histogram (global atomics)
//   2. scan1/scan2: exclusive scan of deg over N (partials applied at use)
//   3. scatter: pos = atomicAdd(&S[d],1) + P[d>>10]; staged[pos]={src, leaky}
//      (the adds turn S into per-dst END offsets in place — no sort kernel)
//   4. aggregate: block=4 waves=4 consecutive dsts, contiguous edata span
//      staged to LDS; per-wave softmax (max -> exp-sum, weights cached in LDS)
//      fused with the weighted gather (16 lanes/edge x 4 slots, 4 gathers in
//      flight per lane).
//
// ws: ftb | s_l | s_r | deg (N u32) | S (N u32) | partials (1024) |
//     Wswz (2048x16B) | staged/edata (E uint2)

#define ALPHA 0.2f
#define HB 512             // histogram blocks in front
#define ESLOTS 1024        // aggregate edata LDS staging slots (mean span 64)

typedef __attribute__((ext_vector_type(8))) short bf16x8;
typedef __attribute__((ext_vector_type(8))) unsigned short u16x8;
typedef __attribute__((ext_vector_type(4))) float f32x4;

__device__ __forceinline__ unsigned short f2bf(float f) {
    unsigned u = __float_as_uint(f);
    unsigned r = (u + 0x7FFFu + ((u >> 16) & 1u)) >> 16;   // RNE
    return (unsigned short)r;
}

// ---------- prep: build swizzled bf16 W^T + zero deg ----------
__global__ __launch_bounds__(256) void prep_kernel(const float* __restrict__ W,
                                                   u16x8* __restrict__ Wswz,
                                                   unsigned* __restrict__ deg, int N) {
    int gt = blockIdx.x * 256 + threadIdx.x;
    if (gt < 2048) {
        int n = gt >> 4, c = gt & 15;
        u16x8 v;
        #pragma unroll
        for (int j = 0; j < 8; ++j) v[j] = f2bf(W[(c * 8 + j) * 128 + n]);
        Wswz[n * 16 + (c ^ (n & 7))] = v;
    }
    if (gt < N) deg[gt] = 0u;
}

// ---------- front: fused MFMA GEMM + per-dst degree histogram ----------
__global__ __launch_bounds__(256) void front_kernel(
        const float* __restrict__ A, const u16x8* __restrict__ Wswz,
        const float* __restrict__ attn_l, const float* __restrict__ attn_r,
        unsigned short* __restrict__ ftb,
        float* __restrict__ s_l, float* __restrict__ s_r, int N, int GB,
        const int* __restrict__ dst, unsigned* __restrict__ deg,
        int E, int slice) {
    __shared__ char smem[49152];
    const int tid = threadIdx.x;

    if (blockIdx.x >= (unsigned)GB) {
        // ---------------- degree histogram body ----------------
        const int b = blockIdx.x - GB;
        int s0 = b * slice, s1 = min(s0 + slice, E);
        for (int i = s0 + tid; i < s1; i += 256)
            atomicAdd(&deg[(unsigned)dst[i]], 1u);
        return;
    }

    // ---------------- gemm body ----------------
    u16x8* A_lds = (u16x8*)smem;                 // 64 rows x 16 chunks (16 KB)
    u16x8* W_lds = (u16x8*)(smem + 16384);       // 128 n x 16 chunks (32 KB)
    const int block_row = blockIdx.x * 64;

    for (int i = tid; i < 2048; i += 256) W_lds[i] = Wswz[i];

    for (int l = tid; l < 1024; l += 256) {
        int m = l >> 4, c = l & 15;
        int row = block_row + m;
        float4 v0 = make_float4(0.f, 0.f, 0.f, 0.f), v1 = v0;
        if (row < N) {
            const float4* p = (const float4*)(A + (size_t)row * 128 + c * 8);
            v0 = p[0]; v1 = p[1];
        }
        u16x8 u;
        u[0] = f2bf(v0.x); u[1] = f2bf(v0.y); u[2] = f2bf(v0.z); u[3] = f2bf(v0.w);
        u[4] = f2bf(v1.x); u[5] = f2bf(v1.y); u[6] = f2bf(v1.z); u[7] = f2bf(v1.w);
        A_lds[m * 16 + (c ^ (m & 7))] = u;
    }
    __syncthreads();

    const int wv = tid >> 6;
    const int lane = tid & 63;
    const int lm = lane & 15;
    const int quad = lane >> 4;

    f32x4 acc[8];
    #pragma unroll
    for (int t = 0; t < 8; ++t) acc[t] = (f32x4)(0.f);

    const int am = wv * 16 + lm;
    #pragma unroll
    for (int ks = 0; ks < 4; ++ks) {
        int c = ks * 4 + quad;
        bf16x8 af = *(const bf16x8*)&A_lds[am * 16 + (c ^ (am & 7))];
        #pragma unroll
        for (int t = 0; t < 8; ++t) {
            int n = t * 16 + lm;
            bf16x8 bf = *(const bf16x8*)&W_lds[n * 16 + (c ^ (n & 7))];
            acc[t] = __builtin_amdgcn_mfma_f32_16x16x32_bf16(af, bf, acc[t], 0, 0, 0);
        }
    }

    // fused head-0 scores (cols 0..31 live in frags 0,1)
    {
        float al0 = attn_l[lm], al1 = attn_l[16 + lm];
        float ar0 = attn_r[lm], ar1 = attn_r[16 + lm];
        #pragma unroll
        for (int r = 0; r < 4; ++r) {
            float pl = acc[0][r] * al0 + acc[1][r] * al1;
            float pr = acc[0][r] * ar0 + acc[1][r] * ar1;
            #pragma unroll
            for (int mask = 1; mask < 16; mask <<= 1) {
                pl += __shfl_xor(pl, mask, 64);
                pr += __shfl_xor(pr, mask, 64);
            }
            if (lm == 0) {
                int row = block_row + wv * 16 + quad * 4 + r;
                if (row < N) { s_l[row] = pl; s_r[row] = pr; }
            }
        }
    }

    // transpose C through LDS, then coalesced bf16 store
    unsigned short* C_lds = (unsigned short*)A_lds;
    #pragma unroll
    for (int t = 0; t < 8; ++t) {
        #pragma unroll
        for (int r = 0; r < 4; ++r) {
            int mrow = wv * 16 + quad * 4 + r;
            C_lds[mrow * 128 + t * 16 + lm] = f2bf(acc[t][r]);
        }
    }
    __syncthreads();
    for (int l = tid; l < 1024; l += 256) {
        int m = l >> 4, c = l & 15;
        int row = block_row + m;
        if (row < N)
            *(u16x8*)(ftb + (size_t)row * 128 + c * 8) = *(const u16x8*)&C_lds[m * 128 + c * 8];
    }
}

// ---------- scan1: block-local exclusive scan (1024/block) + totals ----------
__global__ __launch_bounds__(256) void scan1_kernel(const unsigned* __restrict__ counts,
                                                    unsigned* __restrict__ S,
                                                    unsigned* __restrict__ partials, int M) {
    __shared__ unsigned sh[256];
    const int tid = threadIdx.x;
    const int base = blockIdx.x * 1024 + tid * 4;
    unsigned v[4];
    unsigned s = 0;
    #pragma unroll
    for (int k = 0; k < 4; ++k) {
        int idx = base + k;
        v[k] = (idx < M) ? counts[idx] : 0u;
        s += v[k];
    }
    sh[tid] = s;
    __syncthreads();
    for (int off = 1; off < 256; off <<= 1) {
        unsigned t = (tid >= off) ? sh[tid - off] : 0u;
        __syncthreads();
        sh[tid] += t;
        __syncthreads();
    }
    if (tid == 255) partials[blockIdx.x] = sh[255];
    unsigned run = (tid == 0) ? 0u : sh[tid - 1];
    #pragma unroll
    for (int k = 0; k < 4; ++k) {
        int idx = base + k;
        if (idx < M) S[idx] = run;
        run += v[k];
    }
}

// ---------- scan2: exclusive scan of block totals (NB <= 1024) ----------
__global__ __launch_bounds__(256) void scan2_kernel(unsigned* __restrict__ partials, int NB) {
    __shared__ unsigned sh[256];
    const int tid = threadIdx.x;
    unsigned v[4];
    unsigned s = 0;
    #pragma unroll
    for (int k = 0; k < 4; ++k) {
        int idx = tid * 4 + k;
        v[k] = (idx < NB) ? partials[idx] : 0u;
        s += v[k];
    }
    sh[tid] = s;
    __syncthreads();
    for (int off = 1; off < 256; off <<= 1) {
        unsigned t = (tid >= off) ? sh[tid - off] : 0u;
        __syncthreads();
        sh[tid] += t;
        __syncthreads();
    }
    unsigned run = (tid == 0) ? 0u : sh[tid - 1];
    #pragma unroll
    for (int k = 0; k < 4; ++k) {
        int idx = tid * 4 + k;
        if (idx < NB) partials[idx] = run;
        run += v[k];
    }
}

// ---------- scatter: staged[excl[d] + n] = {src, leaky_score} ----------
// atomicAdd on S converts the exclusive scan into END offsets in place:
// after this kernel, end[d] = S[d] + P[d>>10], start[d] = end[d-1].
__global__ __launch_bounds__(256) void scatter_kernel(
        const int* __restrict__ src, const int* __restrict__ dst,
        const float* __restrict__ s_l, const float* __restrict__ s_r,
        unsigned* __restrict__ S, const unsigned* __restrict__ P,
        uint2* __restrict__ staged, int E) {
    int i = blockIdx.x * 256 + threadIdx.x;
    if (i >= E) return;
    int s = src[i], d = dst[i];
    float x = s_l[s] + s_r[d];
    float e = (x > 0.f) ? x : ALPHA * x;
    unsigned pos = atomicAdd(&S[d], 1u) + P[((unsigned)d) >> 10];
    staged[pos] = make_uint2((unsigned)s, __float_as_uint(e));
}

// ---------- aggregate: fused per-dst softmax + weighted gather ----------
// Block of 4 waves = 4 consecutive dsts with a contiguous edata span, staged
// cooperatively to LDS. Per wave: max pass (LDS broadcast reads), exp-sum
// pass caching unnormalized weights back into LDS, then the gather loop
// (16 lanes/edge x 4 slots x stride-16 -> 4 gathers in flight per lane).
__global__ __launch_bounds__(256) void aggregate_kernel(
        const uint2* __restrict__ edata, const unsigned* __restrict__ S,
        const unsigned* __restrict__ P,
        const unsigned short* __restrict__ ftb, float* __restrict__ out, int N) {
    __shared__ uint2 elds[ESLOTS];
    const int wv = threadIdx.x >> 6;
    const int lane = threadIdx.x & 63;
    const int eh = lane >> 4;          // edge slot 0..3
    const int j  = lane & 15;          // feat group: feats j*8 .. j*8+7
    const int db = blockIdx.x * 4;
    const int d = db + wv;

    const unsigned bstart = (db == 0) ? 0u : (S[db - 1] + P[(unsigned)(db - 1) >> 10]);
    const int dtop = min(db + 3, N - 1);
    const unsigned bend = S[dtop] + P[(unsigned)dtop >> 10];
    unsigned start = 0u, end = 0u;
    if (d < N) {
        start = (d == 0) ? 0u : (S[d - 1] + P[(unsigned)(d - 1) >> 10]);
        end = S[d] + P[(unsigned)d >> 10];
    }

    float acc[8] = {0.f, 0.f, 0.f, 0.f, 0.f, 0.f, 0.f, 0.f};

    if (bend - bstart <= (unsigned)ESLOTS) {
        // -------- fast path: whole block span staged in LDS --------
        for (unsigned i = threadIdx.x; i < bend - bstart; i += 256)
            elds[i] = edata[bstart + i];
        __syncthreads();
        if (d < N && end > start) {
            // max over this dst's scores (broadcast reads across j-lanes)
            float m = -1e30f;
            for (unsigned i = start + eh; i < end; i += 4)
                m = fmaxf(m, __uint_as_float(elds[i - bstart].y));
            m = fmaxf(m, __shfl_xor(m, 16, 64));
            m = fmaxf(m, __shfl_xor(m, 32, 64));
            // exp-sum; cache unnormalized weights back into LDS
            float s = 0.f;
            for (unsigned i = start + eh; i < end; i += 4) {
                float w = __expf(__uint_as_float(elds[i - bstart].y) - m);
                s += w;
                if (j == 0) elds[i - bstart].y = __float_as_uint(w);
            }
            s += __shfl_xor(s, 16, 64);
            s += __shfl_xor(s, 32, 64);
            float rden = 1.f / s;
            for (unsigned e = start; e < end; e += 16) {
                unsigned i0 = e + eh, i1 = i0 + 4, i2 = i0 + 8, i3 = i0 + 12;
                uint2 e0 = (i0 < end) ? elds[i0 - bstart] : make_uint2(0u, 0u);
                uint2 e1 = (i1 < end) ? elds[i1 - bstart] : make_uint2(0u, 0u);
                uint2 e2 = (i2 < end) ? elds[i2 - bstart] : make_uint2(0u, 0u);
                uint2 e3 = (i3 < end) ? elds[i3 - bstart] : make_uint2(0u, 0u);
                uint4 q0 = *(const uint4*)(ftb + (size_t)e0.x * 128 + j * 8);
                uint4 q1 = *(const uint4*)(ftb + (size_t)e1.x * 128 + j * 8);
                uint4 q2 = *(const uint4*)(ftb + (size_t)e2.x * 128 + j * 8);
                uint4 q3 = *(const uint4*)(ftb + (size_t)e3.x * 128 + j * 8);
                float a0 = __uint_as_float(e0.y) * rden;
                float a1 = __uint_as_float(e1.y) * rden;
                float a2 = __uint_as_float(e2.y) * rden;
                float a3 = __uint_as_float(e3.y) * rden;
                const unsigned* w0 = (const unsigned*)&q0;
                const unsigned* w1 = (const unsigned*)&q1;
                const unsigned* w2 = (const unsigned*)&q2;
                const unsigned* w3 = (const unsigned*)&q3;
                #pragma unroll
                for (int p = 0; p < 4; ++p) {
                    acc[2 * p]     += a0 * __uint_as_float(w0[p] << 16);
                    acc[2 * p + 1] += a0 * __uint_as_float(w0[p] & 0xFFFF0000u);
                    acc[2 * p]     += a1 * __uint_as_float(w1[p] << 16);
                    acc[2 * p + 1] += a1 * __uint_as_float(w1[p] & 0xFFFF0000u);
                    acc[2 * p]     += a2 * __uint_as_float(w2[p] << 16);
                    acc[2 * p + 1] += a2 * __uint_as_float(w2[p] & 0xFFFF0000u);
                    acc[2 * p]     += a3 * __uint_as_float(w3[p] << 16);
                    acc[2 * p + 1] += a3 * __uint_as_float(w3[p] & 0xFFFF0000u);
                }
            }
        }
    } else {
        // -------- slow fallback (statistically never): read global --------
        if (d < N && end > start) {
            float m = -1e30f;
            for (unsigned i = start + eh; i < end; i += 4)
                m = fmaxf(m, __uint_as_float(edata[i].y));
            m = fmaxf(m, __shfl_xor(m, 16, 64));
            m = fmaxf(m, __shfl_xor(m, 32, 64));
            float s = 0.f;
            for (unsigned i = start + eh; i < end; i += 4)
                s += __expf(__uint_as_float(edata[i].y) - m);
            s += __shfl_xor(s, 16, 64);
            s += __shfl_xor(s, 32, 64);
            float rden = 1.f / s;
            for (unsigned e = start; e < end; e += 16) {
                unsigned i0 = e + eh, i1 = i0 + 4, i2 = i0 + 8, i3 = i0 + 12;
                uint2 e0 = (i0 < end) ? edata[i0] : make_uint2(0u, 0u);
                uint2 e1 = (i1 < end) ? edata[i1] : make_uint2(0u, 0u);
                uint2 e2 = (i2 < end) ? edata[i2] : make_uint2(0u, 0u);
                uint2 e3 = (i3 < end) ? edata[i3] : make_uint2(0u, 0u);
                uint4 q0 = *(const uint4*)(ftb + (size_t)e0.x * 128 + j * 8);
                uint4 q1 = *(const uint4*)(ftb + (size_t)e1.x * 128 + j * 8);
                uint4 q2 = *(const uint4*)(ftb + (size_t)e2.x * 128 + j * 8);
                uint4 q3 = *(const uint4*)(ftb + (size_t)e3.x * 128 + j * 8);
                float a0 = (i0 < end) ? __expf(__uint_as_float(e0.y) - m) * rden : 0.f;
                float a1 = (i1 < end) ? __expf(__uint_as_float(e1.y) - m) * rden : 0.f;
                float a2 = (i2 < end) ? __expf(__uint_as_float(e2.y) - m) * rden : 0.f;
                float a3 = (i3 < end) ? __expf(__uint_as_float(e3.y) - m) * rden : 0.f;
                const unsigned* w0 = (const unsigned*)&q0;
                const unsigned* w1 = (const unsigned*)&q1;
                const unsigned* w2 = (const unsigned*)&q2;
                const unsigned* w3 = (const unsigned*)&q3;
                #pragma unroll
                for (int p = 0; p < 4; ++p) {
                    acc[2 * p]     += a0 * __uint_as_float(w0[p] << 16);
                    acc[2 * p + 1] += a0 * __uint_as_float(w0[p] & 0xFFFF0000u);
                    acc[2 * p]     += a1 * __uint_as_float(w1[p] << 16);
                    acc[2 * p + 1] += a1 * __uint_as_float(w1[p] & 0xFFFF0000u);
                    acc[2 * p]     += a2 * __uint_as_float(w2[p] << 16);
                    acc[2 * p + 1] += a2 * __uint_as_float(w2[p] & 0xFFFF0000u);
                    acc[2 * p]     += a3 * __uint_as_float(w3[p] << 16);
                    acc[2 * p + 1] += a3 * __uint_as_float(w3[p] & 0xFFFF0000u);
                }
            }
        }
    }

    #pragma unroll
    for (int p = 0; p < 8; ++p) {
        acc[p] += __shfl_xor(acc[p], 16, 64);
        acc[p] += __shfl_xor(acc[p], 32, 64);
    }
    if (d < N && eh == 0) {
        float4* op = (float4*)(out + (size_t)d * 128 + j * 8);
        op[0] = make_float4(acc[0], acc[1], acc[2], acc[3]);
        op[1] = make_float4(acc[4], acc[5], acc[6], acc[7]);
    }
}

static inline size_t align256(size_t x) { return (x + 255) & ~(size_t)255; }

extern "C" void kernel_launch(void* const* d_in, const int* in_sizes, int n_in,
                              void* d_out, int out_size, void* d_ws, size_t ws_size,
                              hipStream_t stream) {
    const float* inputs = (const float*)d_in[0];
    const int*   src    = (const int*)d_in[1];
    const int*   dst    = (const int*)d_in[2];
    const float* fc_w   = (const float*)d_in[3];
    const float* attn_l = (const float*)d_in[4];
    const float* attn_r = (const float*)d_in[5];
    float* out = (float*)d_out;

    const int N = in_sizes[0] / 128;
    const int E = in_sizes[1];
    const int NB1 = (N + 1023) / 1024;                 // scan1 blocks (98)
    const int slice = (E + HB - 1) / HB;
    const int GB = (N + 63) / 64;                      // gemm blocks

    char* w = (char*)d_ws;
    unsigned short* ftb = (unsigned short*)w;  w += align256((size_t)N * 128 * 2);
    float*    s_l      = (float*)w;     w += align256((size_t)N * 4);
    float*    s_r      = (float*)w;     w += align256((size_t)N * 4);
    unsigned* deg      = (unsigned*)w;  w += align256((size_t)N * 4);
    unsigned* S        = (unsigned*)w;  w += align256((size_t)N * 4);
    unsigned* partials = (unsigned*)w;  w += align256(1024 * 4);
    u16x8*    Wswz     = (u16x8*)w;     w += align256(2048 * 16);
    uint2*    staged   = (uint2*)w;     w += align256((size_t)E * 8);  // edata

    prep_kernel<<<(N + 255) / 256, 256, 0, stream>>>(fc_w, Wswz, deg, N);
    front_kernel<<<GB + HB, 256, 0, stream>>>(inputs, Wswz, attn_l, attn_r,
                                              ftb, s_l, s_r, N, GB,
                                              dst, deg, E, slice);
    scan1_kernel<<<NB1, 256, 0, stream>>>(deg, S, partials, N);
    scan2_kernel<<<1, 256, 0, stream>>>(partials, NB1);
    scatter_kernel<<<(E + 255) / 256, 256, 0, stream>>>(src, dst, s_l, s_r,
                                                        S, partials, staged, E);
    aggregate_kernel<<<(N + 3) / 4, 256, 0, stream>>>(staged, S, partials,
                                                      ftb, out, N);
}

// Round 4
// 246.829 us; speedup vs baseline: 1.3942x; 1.3942x over previous
//
#include <hip/hip_runtime.h>

// GAT forward — MFMA GEMM + two-level bucket CSR + weighted gather:
//   0. prep: build Wswz (bf16 W^T, 16B-chunk XOR swizzle)
//   1. front (fused): blocks [0,GB): MFMA gemm -> ftb + fused head-0 scores
//      (A fragments loaded DIRECT from global, no A_lds; W_lds 32KB reused
//       for the C transpose -> 5 blocks/CU instead of 3);
//      blocks [GB,GB+NBLK): bhist per-(block,bucket) LDS histogram (bucket=dst>>8)
//   2. scan1/scan2: exclusive scan of bh[bucket][block] (partials applied at use)
//   3. bscatter: staged[pos]={src|dlow<<20, leaky_score}, exact pos via LDS bases
//   4. bsort: block/bucket LDS counting sort + per-dst serial softmax; edata={src,a}
//   5. aggregate: block=4 waves=4 consecutive dsts; contiguous edata span staged
//      to LDS; 16 lanes/edge x 4 slots x stride-16 -> 4 gathers in flight/lane.
//
// ws: ftb | s_l | s_r | bh (M u32) | S (M u32) | partials (1024) |
//     offsets (N u32) | Wswz (2048x16B) | staged/edata (E uint2)

#define ALPHA 0.2f
#define NBLK 512           // partition blocks
#define BBITS 8
#define BSIZE 256          // dsts per bucket
#define CAP 5120           // bsort LDS record capacity (mean 4096, +16 sigma)
#define ESLOTS 1024        // aggregate edata LDS staging slots (mean span 64)

typedef __attribute__((ext_vector_type(8))) short bf16x8;
typedef __attribute__((ext_vector_type(8))) unsigned short u16x8;
typedef __attribute__((ext_vector_type(4))) float f32x4;

__device__ __forceinline__ unsigned short f2bf(float f) {
    unsigned u = __float_as_uint(f);
    unsigned r = (u + 0x7FFFu + ((u >> 16) & 1u)) >> 16;   // RNE
    return (unsigned short)r;
}

// ---------- prep: build swizzled bf16 W^T ----------
__global__ __launch_bounds__(256) void prep_kernel(const float* __restrict__ W,
                                                   u16x8* __restrict__ Wswz) {
    int gt = blockIdx.x * 256 + threadIdx.x;
    if (gt < 2048) {
        int n = gt >> 4, c = gt & 15;
        u16x8 v;
        #pragma unroll
        for (int j = 0; j < 8; ++j) v[j] = f2bf(W[(c * 8 + j) * 128 + n]);
        Wswz[n * 16 + (c ^ (n & 7))] = v;
    }
}

// ---------- front: fused MFMA GEMM + bhist ----------
__global__ __launch_bounds__(256) void front_kernel(
        const float* __restrict__ A, const u16x8* __restrict__ Wswz,
        const float* __restrict__ attn_l, const float* __restrict__ attn_r,
        unsigned short* __restrict__ ftb,
        float* __restrict__ s_l, float* __restrict__ s_r, int N, int GB,
        const int* __restrict__ dst, unsigned* __restrict__ bh,
        int E, int nbucket, int slice) {
    __shared__ char smem[32768];
    const int tid = threadIdx.x;

    if (blockIdx.x >= (unsigned)GB) {
        // ---------------- bhist body ----------------
        unsigned* cnt = (unsigned*)smem;
        for (int i = tid; i < nbucket; i += 256) cnt[i] = 0u;
        __syncthreads();
        const int b = blockIdx.x - GB;
        int s0 = b * slice, s1 = min(s0 + slice, E);
        for (int i = s0 + tid; i < s1; i += 256)
            atomicAdd(&cnt[((unsigned)dst[i]) >> BBITS], 1u);
        __syncthreads();
        for (int k = tid; k < nbucket; k += 256)
            bh[(size_t)k * NBLK + b] = cnt[k];
        return;
    }

    // ---------------- gemm body ----------------
    u16x8* W_lds = (u16x8*)smem;                 // 128 n x 16 chunks (32 KB)
    const int block_row = blockIdx.x * 64;

    for (int i = tid; i < 2048; i += 256) W_lds[i] = Wswz[i];

    const int wv = tid >> 6;
    const int lane = tid & 63;
    const int lm = lane & 15;
    const int quad = lane >> 4;
    const int am = block_row + wv * 16 + lm;     // global A row for this lane
    const bool rowok = (am < N);

    // A fragments direct from global (16B/lane contiguous per k-chunk)
    bf16x8 a_frag[4];
    #pragma unroll
    for (int ks = 0; ks < 4; ++ks) {
        int c = ks * 4 + quad;
        float4 v0 = make_float4(0.f, 0.f, 0.f, 0.f), v1 = v0;
        if (rowok) {
            const float4* p = (const float4*)(A + (size_t)am * 128 + c * 8);
            v0 = p[0]; v1 = p[1];
        }
        u16x8 u;
        u[0] = f2bf(v0.x); u[1] = f2bf(v0.y); u[2] = f2bf(v0.z); u[3] = f2bf(v0.w);
        u[4] = f2bf(v1.x); u[5] = f2bf(v1.y); u[6] = f2bf(v1.z); u[7] = f2bf(v1.w);
        a_frag[ks] = *(const bf16x8*)&u;
    }
    __syncthreads();   // W_lds ready

    f32x4 acc[8];
    #pragma unroll
    for (int t = 0; t < 8; ++t) acc[t] = (f32x4)(0.f);

    #pragma unroll
    for (int ks = 0; ks < 4; ++ks) {
        int c = ks * 4 + quad;
        #pragma unroll
        for (int t = 0; t < 8; ++t) {
            int n = t * 16 + lm;
            bf16x8 bf = *(const bf16x8*)&W_lds[n * 16 + (c ^ (n & 7))];
            acc[t] = __builtin_amdgcn_mfma_f32_16x16x32_bf16(a_frag[ks], bf, acc[t], 0, 0, 0);
        }
    }

    // fused head-0 scores (cols 0..31 live in frags 0,1)
    {
        float al0 = attn_l[lm], al1 = attn_l[16 + lm];
        float ar0 = attn_r[lm], ar1 = attn_r[16 + lm];
        #pragma unroll
        for (int r = 0; r < 4; ++r) {
            float pl = acc[0][r] * al0 + acc[1][r] * al1;
            float pr = acc[0][r] * ar0 + acc[1][r] * ar1;
            #pragma unroll
            for (int mask = 1; mask < 16; mask <<= 1) {
                pl += __shfl_xor(pl, mask, 64);
                pr += __shfl_xor(pr, mask, 64);
            }
            if (lm == 0) {
                int row = block_row + wv * 16 + quad * 4 + r;
                if (row < N) { s_l[row] = pl; s_r[row] = pr; }
            }
        }
    }

    // transpose C through LDS (reusing W_lds), then coalesced bf16 store
    __syncthreads();   // all waves done reading W_lds
    unsigned short* C_lds = (unsigned short*)smem;
    #pragma unroll
    for (int t = 0; t < 8; ++t) {
        #pragma unroll
        for (int r = 0; r < 4; ++r) {
            int mrow = wv * 16 + quad * 4 + r;
            C_lds[mrow * 128 + t * 16 + lm] = f2bf(acc[t][r]);
        }
    }
    __syncthreads();
    for (int l = tid; l < 1024; l += 256) {
        int m = l >> 4, c = l & 15;
        int row = block_row + m;
        if (row < N)
            *(u16x8*)(ftb + (size_t)row * 128 + c * 8) = *(const u16x8*)&C_lds[m * 128 + c * 8];
    }
}

// ---------- scan1: block-local exclusive scan (1024/block) + totals ----------
__global__ __launch_bounds__(256) void scan1_kernel(const unsigned* __restrict__ counts,
                                                    unsigned* __restrict__ S,
                                                    unsigned* __restrict__ partials, int M) {
    __shared__ unsigned sh[256];
    const int tid = threadIdx.x;
    const int base = blockIdx.x * 1024 + tid * 4;
    unsigned v[4];
    unsigned s = 0;
    #pragma unroll
    for (int k = 0; k < 4; ++k) {
        int idx = base + k;
        v[k] = (idx < M) ? counts[idx] : 0u;
        s += v[k];
    }
    sh[tid] = s;
    __syncthreads();
    for (int off = 1; off < 256; off <<= 1) {
        unsigned t = (tid >= off) ? sh[tid - off] : 0u;
        __syncthreads();
        sh[tid] += t;
        __syncthreads();
    }
    if (tid == 255) partials[blockIdx.x] = sh[255];
    unsigned run = (tid == 0) ? 0u : sh[tid - 1];
    #pragma unroll
    for (int k = 0; k < 4; ++k) {
        int idx = base + k;
        if (idx < M) S[idx] = run;
        run += v[k];
    }
}

// ---------- scan2: exclusive scan of block totals (NB <= 1024) ----------
__global__ __launch_bounds__(256) void scan2_kernel(unsigned* __restrict__ partials, int NB) {
    __shared__ unsigned sh[256];
    const int tid = threadIdx.x;
    unsigned v[4];
    unsigned s = 0;
    #pragma unroll
    for (int k = 0; k < 4; ++k) {
        int idx = tid * 4 + k;
        v[k] = (idx < NB) ? partials[idx] : 0u;
        s += v[k];
    }
    sh[tid] = s;
    __syncthreads();
    for (int off = 1; off < 256; off <<= 1) {
        unsigned t = (tid >= off) ? sh[tid - off] : 0u;
        __syncthreads();
        sh[tid] += t;
        __syncthreads();
    }
    unsigned run = (tid == 0) ? 0u : sh[tid - 1];
    #pragma unroll
    for (int k = 0; k < 4; ++k) {
        int idx = tid * 4 + k;
        if (idx < NB) partials[idx] = run;
        run += v[k];
    }
}

// ---------- bscatter: staged[pos] = {src | dlow<<20, leaky_score} ----------
// partials folded in here: base preloaded to LDS per block.
__global__ __launch_bounds__(256) void bscatter_kernel(
        const int* __restrict__ src, const int* __restrict__ dst,
        const float* __restrict__ s_l, const float* __restrict__ s_r,
        const unsigned* __restrict__ S, const unsigned* __restrict__ partials,
        uint2* __restrict__ staged, int E, int nbucket, int slice) {
    __shared__ unsigned basel[512];
    __shared__ unsigned cur[512];
    const int b = blockIdx.x;
    for (int k = threadIdx.x; k < nbucket; k += 256) {
        unsigned idx = (unsigned)k * NBLK + b;
        basel[k] = S[idx] + partials[idx >> 10];
        cur[k] = 0u;
    }
    __syncthreads();
    int s0 = b * slice, s1 = min(s0 + slice, E);
    for (int i = s0 + threadIdx.x; i < s1; i += 256) {
        int s = src[i], d = dst[i];
        unsigned k = ((unsigned)d) >> BBITS;
        float x = s_l[s] + s_r[d];
        float e = (x > 0.f) ? x : ALPHA * x;
        unsigned pos = basel[k] + atomicAdd(&cur[k], 1u);
        staged[pos] = make_uint2((unsigned)s | (((unsigned)d & (BSIZE - 1)) << 20),
                                 __float_as_uint(e));
    }
}

// ---------- bsort: per-bucket counting sort + softmax; in-place rewrite ----------
__global__ __launch_bounds__(256) void bsort_kernel(
        uint2* __restrict__ staged, const unsigned* __restrict__ S,
        const unsigned* __restrict__ partials,
        unsigned* __restrict__ offsets, int N, int E, int nbucket) {
    __shared__ uint2 rec[CAP];
    __shared__ unsigned cnt[BSIZE], incl[BSIZE], cur[BSIZE];
    const int k = blockIdx.x;
    const int t = threadIdx.x;
    unsigned idx0 = (unsigned)k * NBLK;
    unsigned gstart = S[idx0] + partials[idx0 >> 10];
    unsigned gend = (k + 1 == nbucket) ? (unsigned)E
                                       : (S[idx0 + NBLK] + partials[(idx0 + NBLK) >> 10]);
    int n = (int)(gend - gstart);
    if (n > CAP) n = CAP;   // statistically impossible; avoid corruption

    cnt[t] = 0u;
    __syncthreads();
    for (int i = t; i < n; i += 256)
        atomicAdd(&cnt[staged[gstart + i].x >> 20], 1u);
    __syncthreads();
    incl[t] = cnt[t];
    __syncthreads();
    for (int off = 1; off < 256; off <<= 1) {
        unsigned u = (t >= off) ? incl[t - off] : 0u;
        __syncthreads();
        incl[t] += u;
        __syncthreads();
    }
    cur[t] = 0u;
    __syncthreads();
    for (int i = t; i < n; i += 256) {
        uint2 r = staged[gstart + i];
        unsigned dl = r.x >> 20;
        unsigned p = incl[dl] - cnt[dl] + atomicAdd(&cur[dl], 1u);
        rec[p] = r;
    }
    __syncthreads();
    int d = k * BSIZE + t;
    if (d < N) {
        int b0 = (int)(incl[t] - cnt[t]);
        int c = (int)cnt[t];
        float m = -1e30f;
        for (int j = 0; j < c; ++j) m = fmaxf(m, __uint_as_float(rec[b0 + j].y));
        float sum = 0.f;
        for (int j = 0; j < c; ++j) sum += __expf(__uint_as_float(rec[b0 + j].y) - m);
        float rden = (c > 0) ? 1.f / sum : 0.f;
        for (int j = 0; j < c; ++j) {
            float a = __expf(__uint_as_float(rec[b0 + j].y) - m) * rden;
            rec[b0 + j].y = __float_as_uint(a);
        }
        offsets[d] = gstart + incl[t];
    }
    __syncthreads();
    for (int i = t; i < n; i += 256) {
        uint2 r = rec[i];
        staged[gstart + i] = make_uint2(r.x & 0xFFFFFu, r.y);
    }
}

// ---------- aggregate: weighted gather, wave per node ----------
// Block of 4 waves handles 4 consecutive dsts whose edata range is contiguous:
// cooperative LDS stage of edata (coalesced) removes the edata->gather
// dependent global-latency chain; 16 lanes/edge x 4 slots x stride-16 puts
// 4 gathers in flight per lane (16 edges/wave/iter; mean degree is 16).
__global__ __launch_bounds__(256) void aggregate_kernel(
        const uint2* __restrict__ edata, const unsigned* __restrict__ offsets,
        const unsigned short* __restrict__ ftb, float* __restrict__ out, int N) {
    __shared__ uint2 elds[ESLOTS];
    const int wv = threadIdx.x >> 6;
    const int lane = threadIdx.x & 63;
    const int eh = lane >> 4;          // edge slot 0..3
    const int j  = lane & 15;          // feat group: feats j*8 .. j*8+7
    const int db = blockIdx.x * 4;
    const int d = db + wv;

    const unsigned bstart = (db == 0) ? 0u : offsets[db - 1];
    const unsigned bend = offsets[min(db + 3, N - 1)];
    unsigned start = 0u, end = 0u;
    if (d < N) {
        start = (d == 0) ? 0u : offsets[d - 1];
        end = offsets[d];
    }

    float acc[8] = {0.f, 0.f, 0.f, 0.f, 0.f, 0.f, 0.f, 0.f};

    for (unsigned cbase = bstart; cbase < bend; cbase += ESLOTS) {
        const unsigned cn = min((unsigned)ESLOTS, bend - cbase);
        __syncthreads();
        for (unsigned i = threadIdx.x; i < cn; i += 256)
            elds[i] = edata[cbase + i];
        __syncthreads();
        const unsigned lo = (start > cbase) ? start : cbase;
        const unsigned hi = (end < cbase + cn) ? end : (cbase + cn);
        for (unsigned e = lo; e < hi; e += 16) {
            unsigned i0 = e + eh, i1 = e + 4 + eh, i2 = e + 8 + eh, i3 = e + 12 + eh;
            uint2 e0 = (i0 < hi) ? elds[i0 - cbase] : make_uint2(0u, 0u);  // a=0 pad
            uint2 e1 = (i1 < hi) ? elds[i1 - cbase] : make_uint2(0u, 0u);
            uint2 e2 = (i2 < hi) ? elds[i2 - cbase] : make_uint2(0u, 0u);
            uint2 e3 = (i3 < hi) ? elds[i3 - cbase] : make_uint2(0u, 0u);
            uint4 q0 = *(const uint4*)(ftb + (size_t)e0.x * 128 + j * 8);
            uint4 q1 = *(const uint4*)(ftb + (size_t)e1.x * 128 + j * 8);
            uint4 q2 = *(const uint4*)(ftb + (size_t)e2.x * 128 + j * 8);
            uint4 q3 = *(const uint4*)(ftb + (size_t)e3.x * 128 + j * 8);
            float a0 = __uint_as_float(e0.y);
            float a1 = __uint_as_float(e1.y);
            float a2 = __uint_as_float(e2.y);
            float a3 = __uint_as_float(e3.y);
            const unsigned* w0 = (const unsigned*)&q0;
            const unsigned* w1 = (const unsigned*)&q1;
            const unsigned* w2 = (const unsigned*)&q2;
            const unsigned* w3 = (const unsigned*)&q3;
            #pragma unroll
            for (int p = 0; p < 4; ++p) {
                acc[2 * p]     += a0 * __uint_as_float(w0[p] << 16);
                acc[2 * p + 1] += a0 * __uint_as_float(w0[p] & 0xFFFF0000u);
                acc[2 * p]     += a1 * __uint_as_float(w1[p] << 16);
                acc[2 * p + 1] += a1 * __uint_as_float(w1[p] & 0xFFFF0000u);
                acc[2 * p]     += a2 * __uint_as_float(w2[p] << 16);
                acc[2 * p + 1] += a2 * __uint_as_float(w2[p] & 0xFFFF0000u);
                acc[2 * p]     += a3 * __uint_as_float(w3[p] << 16);
                acc[2 * p + 1] += a3 * __uint_as_float(w3[p] & 0xFFFF0000u);
            }
        }
    }
    #pragma unroll
    for (int p = 0; p < 8; ++p) {
        acc[p] += __shfl_xor(acc[p], 16, 64);
        acc[p] += __shfl_xor(acc[p], 32, 64);
    }
    if (d < N && eh == 0) {
        float4* op = (float4*)(out + (size_t)d * 128 + j * 8);
        op[0] = make_float4(acc[0], acc[1], acc[2], acc[3]);
        op[1] = make_float4(acc[4], acc[5], acc[6], acc[7]);
    }
}

static inline size_t align256(size_t x) { return (x + 255) & ~(size_t)255; }

extern "C" void kernel_launch(void* const* d_in, const int* in_sizes, int n_in,
                              void* d_out, int out_size, void* d_ws, size_t ws_size,
                              hipStream_t stream) {
    const float* inputs = (const float*)d_in[0];
    const int*   src    = (const int*)d_in[1];
    const int*   dst    = (const int*)d_in[2];
    const float* fc_w   = (const float*)d_in[3];
    const float* attn_l = (const float*)d_in[4];
    const float* attn_r = (const float*)d_in[5];
    float* out = (float*)d_out;

    const int N = in_sizes[0] / 128;
    const int E = in_sizes[1];
    const int nbucket = (N + BSIZE - 1) / BSIZE;       // 391
    const int M = nbucket * NBLK;                      // 200192
    const int NB1 = (M + 1023) / 1024;                 // scan1 blocks (<=1024)
    const int slice = (E + NBLK - 1) / NBLK;
    const int GB = (N + 63) / 64;                      // gemm blocks

    char* w = (char*)d_ws;
    unsigned short* ftb = (unsigned short*)w;  w += align256((size_t)N * 128 * 2);
    float*    s_l      = (float*)w;     w += align256((size_t)N * 4);
    float*    s_r      = (float*)w;     w += align256((size_t)N * 4);
    unsigned* bh       = (unsigned*)w;  w += align256((size_t)M * 4);
    unsigned* S        = (unsigned*)w;  w += align256((size_t)M * 4);
    unsigned* partials = (unsigned*)w;  w += align256(1024 * 4);
    unsigned* offsets  = (unsigned*)w;  w += align256((size_t)N * 4);
    u16x8*    Wswz     = (u16x8*)w;     w += align256(2048 * 16);
    uint2*    staged   = (uint2*)w;     w += align256((size_t)E * 8);  // final edata

    prep_kernel<<<8, 256, 0, stream>>>(fc_w, Wswz);
    front_kernel<<<GB + NBLK, 256, 0, stream>>>(inputs, Wswz, attn_l, attn_r,
                                                ftb, s_l, s_r, N, GB,
                                                dst, bh, E, nbucket, slice);
    scan1_kernel<<<NB1, 256, 0, stream>>>(bh, S, partials, M);
    scan2_kernel<<<1, 256, 0, stream>>>(partials, NB1);
    bscatter_kernel<<<NBLK, 256, 0, stream>>>(src, dst, s_l, s_r, S, partials,
                                              staged, E, nbucket, slice);
    bsort_kernel<<<nbucket, 256, 0, stream>>>(staged, S, partials, offsets,
                                              N, E, nbucket);
    aggregate_kernel<<<(N + 3) / 4, 256, 0, stream>>>(staged, offsets, ftb, out, N);
}